// Round 4
// baseline (1519.221 us; speedup 1.0000x reference)
//
#include <hip/hip_runtime.h>
#include <hip/hip_bf16.h>
#include <math.h>
#include <stdint.h>

// ---------------------------------------------------------------------------
// GCN 4-layer, bf16 datapath:
//   h = relu( A_w @ (h @ W) + b ) x4, then log_softmax (fp32 out).
//   - dst-CSR built once; edges packed to u32 (src<<15 | w*32767)
//   - GEMM: bf16 MFMA 16x16x32, tile 128x64, BK=64, global_load_lds staging,
//     epilogue writes support PANEL-MAJOR S[pg][node][P] (8 panel groups)
//   - SpMM: grid (8, chunks); blockIdx.x = panel group -> XCD (round-robin),
//     so each XCD's random gathers hit a <=6.4MB slice resident in its 4MB L2
// ---------------------------------------------------------------------------

#define WAVE 64
typedef __attribute__((ext_vector_type(8))) short short8;
typedef __attribute__((ext_vector_type(4))) float floatx4;

__device__ __forceinline__ void async_copy16(const void* g, void* l) {
    __builtin_amdgcn_global_load_lds(
        (const __attribute__((address_space(1))) void*)g,
        (__attribute__((address_space(3))) void*)l, 16, 0, 0);
}
__device__ __forceinline__ float bf2f(unsigned short u) {
    union { unsigned int i; float f; } x; x.i = ((unsigned int)u) << 16; return x.f;
}

// ---------------- setup conversions ----------------

__global__ __launch_bounds__(256) void convert_x_kernel(const float* __restrict__ in,
                                                        __hip_bfloat16* __restrict__ out,
                                                        long n4) {
    long i = ((long)blockIdx.x * 256 + threadIdx.x);
    if (i >= n4) return;
    const float4 v = *(const float4*)(in + i * 4);
    __hip_bfloat16* o = out + i * 4;
    o[0] = __float2bfloat16(v.x); o[1] = __float2bfloat16(v.y);
    o[2] = __float2bfloat16(v.z); o[3] = __float2bfloat16(v.w);
}

// W [K][N] fp32 -> Wt [Npad][K] bf16 (rows >= N zeroed)
__global__ __launch_bounds__(256) void transpose_w_kernel(const float* __restrict__ W,
                                                          __hip_bfloat16* __restrict__ Wt,
                                                          int K, int N, int Npad) {
    int idx = blockIdx.x * 256 + threadIdx.x;
    if (idx >= Npad * K) return;
    int n = idx / K, k = idx - n * K;
    float v = (n < N) ? W[(size_t)k * N + n] : 0.f;
    Wt[idx] = __float2bfloat16(v);
}

__global__ void pad_bias_kernel(const float* __restrict__ b, float* __restrict__ bp,
                                int n, int npad) {
    int i = threadIdx.x;
    if (i < npad) bp[i] = (i < n) ? b[i] : 0.f;
}

// ---------------- CSR build ----------------

__global__ __launch_bounds__(256) void hist_kernel(const int* __restrict__ dst,
                                                   int nE, int* __restrict__ counts) {
    int i = blockIdx.x * 256 + threadIdx.x;
    if (i < nE) atomicAdd(&counts[dst[i]], 1);
}

__global__ __launch_bounds__(1024) void scan1_kernel(const int* __restrict__ counts,
                                                     int n, int* __restrict__ partial,
                                                     int* __restrict__ bsum) {
    __shared__ int sm[1024];
    int tid = threadIdx.x;
    int i = blockIdx.x * 1024 + tid;
    int x = (i < n) ? counts[i] : 0;
    sm[tid] = x;
    __syncthreads();
    for (int off = 1; off < 1024; off <<= 1) {
        int add = 0;
        if (tid >= off) add = sm[tid - off];
        __syncthreads();
        if (tid >= off) sm[tid] += add;
        __syncthreads();
    }
    int incl = sm[tid];
    if (i < n) partial[i] = incl - x;
    if (tid == 1023) bsum[blockIdx.x] = incl;
}

__global__ __launch_bounds__(1024) void scan2_kernel(const int* __restrict__ bsum,
                                                     int nb, int* __restrict__ boff) {
    __shared__ int sm[1024];
    int tid = threadIdx.x;
    int x = (tid < nb) ? bsum[tid] : 0;
    sm[tid] = x;
    __syncthreads();
    for (int off = 1; off < 1024; off <<= 1) {
        int add = 0;
        if (tid >= off) add = sm[tid - off];
        __syncthreads();
        if (tid >= off) sm[tid] += add;
        __syncthreads();
    }
    if (tid < nb) boff[tid] = sm[tid] - x;
}

__global__ __launch_bounds__(256) void scan3_kernel(int* __restrict__ row_ptr,
                                                    const int* __restrict__ boff,
                                                    int n, int nE,
                                                    int* __restrict__ row_cur) {
    int i = blockIdx.x * 256 + threadIdx.x;
    if (i < n) {
        int v = row_ptr[i] + boff[i >> 10];
        row_ptr[i] = v;
        row_cur[i] = v;
    }
    if (i == 0) row_ptr[n] = nE;
}

// pack: (src << 15) | round(w * 32767);  w in [0,1), src < 2^17
__global__ __launch_bounds__(256) void scatter_kernel(const int* __restrict__ src,
                                                      const int* __restrict__ dst,
                                                      const float* __restrict__ ew,
                                                      int nE,
                                                      int* __restrict__ row_cur,
                                                      unsigned int* __restrict__ edge_pk) {
    int i = blockIdx.x * 256 + threadIdx.x;
    if (i < nE) {
        int d = dst[i];
        int pos = atomicAdd(&row_cur[d], 1);
        unsigned int w15 = (unsigned int)(ew[i] * 32767.f + 0.5f);
        if (w15 > 32767u) w15 = 32767u;
        edge_pk[pos] = ((unsigned int)src[i] << 15) | w15;
    }
}

// ---------------- bf16 MFMA GEMM: C = A[M,K] @ Wt[Npitch,K]^T ---------------
// PANEL: epilogue writes C panel-major S[pg][M][PANEL], pg = gn/PANEL.

template <int PANEL>
__global__ __launch_bounds__(256) void gemm_bf16(const __hip_bfloat16* __restrict__ A,
                                                 const __hip_bfloat16* __restrict__ Wt,
                                                 __hip_bfloat16* __restrict__ C,
                                                 int M, int K, int Npitch) {
    __shared__ __align__(16) __hip_bfloat16 sA[128 * 64];  // [row][k], 128B rows
    __shared__ __align__(16) __hip_bfloat16 sB[64 * 64];   // [n][k],   128B rows
    const int t = threadIdx.x;
    const int lane = t & 63;
    const int w = t >> 6;
    const int wy = w >> 1, wx = w & 1;
    const int quad = lane >> 4;
    const int l16 = lane & 15;
    const int row0 = blockIdx.y * 128;
    const int col0 = blockIdx.x * 64;

    floatx4 acc[4][2];
#pragma unroll
    for (int mt = 0; mt < 4; mt++)
#pragma unroll
        for (int nt = 0; nt < 2; nt++) acc[mt][nt] = 0;

    const int arow = t >> 3;
    const int koff = (t & 7) * 8;

    for (int k0 = 0; k0 < K; k0 += 64) {
#pragma unroll
        for (int r = 0; r < 4; r++) {
            int gm = row0 + r * 32 + arow;
            int gmc = (gm < M) ? gm : 0;
            async_copy16(A + (size_t)gmc * K + k0 + koff,
                         (char*)sA + r * 4096 + t * 16);
        }
#pragma unroll
        for (int r = 0; r < 2; r++) {
            int n = r * 32 + arow;
            async_copy16(Wt + (size_t)(col0 + n) * K + k0 + koff,
                         (char*)sB + r * 4096 + t * 16);
        }
        __syncthreads();

        short8 af[4][2], bfr[2][2];
#pragma unroll
        for (int mt = 0; mt < 4; mt++)
#pragma unroll
            for (int kk = 0; kk < 2; kk++)
                af[mt][kk] = *(const short8*)((const char*)sA +
                             (wy * 64 + mt * 16 + l16) * 128 + kk * 64 + quad * 16);
#pragma unroll
        for (int nt = 0; nt < 2; nt++)
#pragma unroll
            for (int kk = 0; kk < 2; kk++)
                bfr[nt][kk] = *(const short8*)((const char*)sB +
                              (wx * 32 + nt * 16 + l16) * 128 + kk * 64 + quad * 16);
#pragma unroll
        for (int kk = 0; kk < 2; kk++)
#pragma unroll
            for (int mt = 0; mt < 4; mt++)
#pragma unroll
                for (int nt = 0; nt < 2; nt++)
                    acc[mt][nt] = __builtin_amdgcn_mfma_f32_16x16x32_bf16(
                        af[mt][kk], bfr[nt][kk], acc[mt][nt], 0, 0, 0);
        __syncthreads();
    }

#pragma unroll
    for (int mt = 0; mt < 4; mt++) {
#pragma unroll
        for (int nt = 0; nt < 2; nt++) {
            int gn = col0 + wx * 32 + nt * 16 + l16;
            int gmb = row0 + wy * 64 + mt * 16 + quad * 4;
#pragma unroll
            for (int r = 0; r < 4; r++) {
                int gm = gmb + r;
                if (gm < M) {
                    __hip_bfloat16 v = __float2bfloat16(acc[mt][nt][r]);
                    int pg = gn / PANEL, c = gn % PANEL;
                    C[((size_t)pg * M + gm) * PANEL + c] = v;
                }
            }
        }
    }
}

// ---------------- SpMM, XCD-split panels + bias + relu ----------------------
// grid = (8, node_chunks). blockIdx.x = panel group (XCD round-robin hint).
// L = P/VEC lanes per node, 64/L nodes per wave.

__device__ __forceinline__ void store_val(__hip_bfloat16* p, float v) {
    *p = __float2bfloat16(v);
}
__device__ __forceinline__ void store_val(float* p, float v) { *p = v; }

template <int P, int VEC, int U, typename OT>
__global__ __launch_bounds__(256) void spmm_split(const int* __restrict__ row_ptr,
                                                  const unsigned int* __restrict__ edge_pk,
                                                  const __hip_bfloat16* __restrict__ sup,
                                                  const float* __restrict__ bias,
                                                  OT* __restrict__ out,
                                                  int n_nodes, int D) {
    constexpr int L = P / VEC;        // lanes per node
    constexpr int NPW = 64 / L;       // nodes per wave
    constexpr int NB = 4 * NPW;       // nodes per block
    const int pg = blockIdx.x;
    const int lane = threadIdx.x & 63;
    const int wv = threadIdx.x >> 6;
    const int g = lane / L;
    const int sub = lane - g * L;
    const int node = blockIdx.y * NB + wv * NPW + g;
    if (node >= n_nodes) return;

    int e = row_ptr[node];
    const int end = row_ptr[node + 1];
    const unsigned short* spb = (const unsigned short*)sup +
                                (size_t)pg * n_nodes * P + sub * VEC;
    float acc[VEC];
#pragma unroll
    for (int i = 0; i < VEC; i++) acc[i] = 0.f;

    while (e < end) {
        unsigned int pk[U];
#pragma unroll
        for (int u = 0; u < U; u++) {
            int idx = e + u;
            if (idx >= end) idx = end - 1;   // clamp: stays in this row's range
            pk[u] = edge_pk[idx];
        }
        unsigned int srcs[U]; float wts[U];
#pragma unroll
        for (int u = 0; u < U; u++) {
            srcs[u] = pk[u] >> 15;
            float wq = (float)(pk[u] & 0x7fffu) * (1.f / 32767.f);
            wts[u] = (e + u < end) ? wq : 0.f;   // tail edges contribute 0
        }
        if (VEC == 4) {
            ushort4 v[U];
#pragma unroll
            for (int u = 0; u < U; u++)
                v[u] = *(const ushort4*)(spb + (size_t)srcs[u] * P);
#pragma unroll
            for (int u = 0; u < U; u++) {
                acc[0] += bf2f(v[u].x) * wts[u]; acc[1] += bf2f(v[u].y) * wts[u];
                acc[2] += bf2f(v[u].z) * wts[u]; acc[3] += bf2f(v[u].w) * wts[u];
            }
        } else {
            ushort2 v[U];
#pragma unroll
            for (int u = 0; u < U; u++)
                v[u] = *(const ushort2*)(spb + (size_t)srcs[u] * P);
#pragma unroll
            for (int u = 0; u < U; u++) {
                acc[0] += bf2f(v[u].x) * wts[u]; acc[1] += bf2f(v[u].y) * wts[u];
            }
        }
        e += U;
    }

    const int gcol = pg * P + sub * VEC;
#pragma unroll
    for (int i = 0; i < VEC; i++) {
        float r = acc[i] + bias[gcol + i];
        store_val(&out[(size_t)node * D + gcol + i], r > 0.f ? r : 0.f);
    }
}

// ---------------- log_softmax over 40 classes (input pitch 64, fp32) --------

__global__ __launch_bounds__(256) void logsoftmax40_kernel(const float* __restrict__ h,
                                                           float* __restrict__ out,
                                                           int n_nodes) {
    int row = blockIdx.x * (256 / WAVE) + (threadIdx.x >> 6);
    int lane = threadIdx.x & 63;
    if (row >= n_nodes) return;
    float v = (lane < 40) ? h[(size_t)row * 64 + lane] : -INFINITY;
    float m = v;
#pragma unroll
    for (int off = 32; off; off >>= 1) m = fmaxf(m, __shfl_xor(m, off));
    float e = (lane < 40) ? __expf(v - m) : 0.f;
    float s = e;
#pragma unroll
    for (int off = 32; off; off >>= 1) s += __shfl_xor(s, off);
    if (lane < 40) out[(size_t)row * 40 + lane] = v - m - __logf(s);
}

// ---------------- launch ----------------------------------------------------

extern "C" void kernel_launch(void* const* d_in, const int* in_sizes, int n_in,
                              void* d_out, int out_size, void* d_ws, size_t ws_size,
                              hipStream_t stream) {
    const float* x    = (const float*)d_in[0];
    const int*   esrc = (const int*)d_in[1];
    const int*   edst = (const int*)d_in[2];
    const float* ew   = (const float*)d_in[3];
    const float* Wm[4] = {(const float*)d_in[4], (const float*)d_in[6],
                          (const float*)d_in[8], (const float*)d_in[10]};
    const float* bm[4] = {(const float*)d_in[5], (const float*)d_in[7],
                          (const float*)d_in[9], (const float*)d_in[11]};
    const int NFEAT = 512;
    const int n_nodes = in_sizes[0] / NFEAT;
    const int n_edges = in_sizes[1];
    float* out = (float*)d_out;

    // --- workspace carve ---
    char* wsp = (char*)d_ws;
    size_t off = 0;
    auto alloc = [&](size_t bytes) -> void* {
        void* p = wsp + off;
        off += (bytes + 255) & ~(size_t)255;
        return p;
    };
    __hip_bfloat16* Xb = (__hip_bfloat16*)alloc((size_t)n_nodes * 512 * sizeof(__hip_bfloat16));
    __hip_bfloat16* Sb = (__hip_bfloat16*)alloc((size_t)n_nodes * 256 * sizeof(__hip_bfloat16));
    __hip_bfloat16* Hb = (__hip_bfloat16*)alloc((size_t)n_nodes * 256 * sizeof(__hip_bfloat16));
    __hip_bfloat16* Wt1 = (__hip_bfloat16*)alloc(256 * 512 * sizeof(__hip_bfloat16));
    __hip_bfloat16* Wt2 = (__hip_bfloat16*)alloc(128 * 256 * sizeof(__hip_bfloat16));
    __hip_bfloat16* Wt3 = (__hip_bfloat16*)alloc(64 * 128 * sizeof(__hip_bfloat16));
    __hip_bfloat16* Wt4 = (__hip_bfloat16*)alloc(64 * 64 * sizeof(__hip_bfloat16));
    float* b4p     = (float*)alloc(64 * sizeof(float));
    int*   counts  = (int*)alloc((size_t)n_nodes * sizeof(int));
    int*   row_ptr = (int*)alloc(((size_t)n_nodes + 1) * sizeof(int));
    int*   row_cur = (int*)alloc((size_t)n_nodes * sizeof(int));
    int*   bsum    = (int*)alloc(1024 * sizeof(int));
    int*   boff    = (int*)alloc(1024 * sizeof(int));
    unsigned int* edge_pk = (unsigned int*)alloc((size_t)n_edges * sizeof(unsigned int));
    // G4 (L4 fp32 output, pitch 64) aliases Xb — Xb is dead after the L1 GEMM.
    float* G4 = (float*)Xb;
    (void)ws_size;

    // --- conversions ---
    long n4 = (long)n_nodes * 512 / 4;
    convert_x_kernel<<<(int)((n4 + 255) / 256), 256, 0, stream>>>(x, Xb, n4);
    transpose_w_kernel<<<(256 * 512 + 255) / 256, 256, 0, stream>>>(Wm[0], Wt1, 512, 256, 256);
    transpose_w_kernel<<<(128 * 256 + 255) / 256, 256, 0, stream>>>(Wm[1], Wt2, 256, 128, 128);
    transpose_w_kernel<<<(64 * 128 + 255) / 256, 256, 0, stream>>>(Wm[2], Wt3, 128, 64, 64);
    transpose_w_kernel<<<(64 * 64 + 255) / 256, 256, 0, stream>>>(Wm[3], Wt4, 64, 40, 64);
    pad_bias_kernel<<<1, 64, 0, stream>>>(bm[3], b4p, 40, 64);

    // --- CSR build ---
    hipMemsetAsync(counts, 0, (size_t)n_nodes * sizeof(int), stream);
    hist_kernel<<<(n_edges + 255) / 256, 256, 0, stream>>>(edst, n_edges, counts);
    int nb = (n_nodes + 1023) / 1024;
    scan1_kernel<<<nb, 1024, 0, stream>>>(counts, n_nodes, row_ptr, bsum);
    scan2_kernel<<<1, 1024, 0, stream>>>(bsum, nb, boff);
    scan3_kernel<<<(n_nodes + 255) / 256, 256, 0, stream>>>(row_ptr, boff, n_nodes,
                                                            n_edges, row_cur);
    scatter_kernel<<<(n_edges + 255) / 256, 256, 0, stream>>>(esrc, edst, ew, n_edges,
                                                              row_cur, edge_pk);

    // --- layers ---
    dim3 gemm_grid_l1(256 / 64, (n_nodes + 127) / 128);
    dim3 gemm_grid_l2(128 / 64, (n_nodes + 127) / 128);
    dim3 gemm_grid_l34(64 / 64, (n_nodes + 127) / 128);

    // L1: 512 -> 256  (panel P=32, 8 groups; VEC=4 -> 8 lanes/node)
    gemm_bf16<32><<<gemm_grid_l1, 256, 0, stream>>>(Xb, Wt1, Sb, n_nodes, 512, 256);
    spmm_split<32, 4, 4, __hip_bfloat16>
        <<<dim3(8, (n_nodes + 31) / 32), 256, 0, stream>>>(
            row_ptr, edge_pk, Sb, bm[0], Hb, n_nodes, 256);

    // L2: 256 -> 128  (panel P=16; VEC=4 -> 4 lanes/node)
    gemm_bf16<16><<<gemm_grid_l2, 256, 0, stream>>>(Hb, Wt2, Sb, n_nodes, 256, 128);
    spmm_split<16, 4, 4, __hip_bfloat16>
        <<<dim3(8, (n_nodes + 63) / 64), 256, 0, stream>>>(
            row_ptr, edge_pk, Sb, bm[1], Hb, n_nodes, 128);

    // L3: 128 -> 64   (panel P=8; VEC=2 -> 4 lanes/node)
    gemm_bf16<8><<<gemm_grid_l34, 256, 0, stream>>>(Hb, Wt3, Sb, n_nodes, 128, 64);
    spmm_split<8, 2, 8, __hip_bfloat16>
        <<<dim3(8, (n_nodes + 63) / 64), 256, 0, stream>>>(
            row_ptr, edge_pk, Sb, bm[2], Hb, n_nodes, 64);

    // L4: 64 -> 40 (N padded to 64; padded support cols/bias are zero)
    gemm_bf16<8><<<gemm_grid_l34, 256, 0, stream>>>(Hb, Wt4, Sb, n_nodes, 64, 64);
    spmm_split<8, 2, 8, float>
        <<<dim3(8, (n_nodes + 63) / 64), 256, 0, stream>>>(
            row_ptr, edge_pk, Sb, b4p, G4, n_nodes, 64);

    // final log_softmax (reads pitch-64 fp32, writes [n,40] fp32)
    logsoftmax40_kernel<<<(n_nodes + 3) / 4, 256, 0, stream>>>(G4, out, n_nodes);
}

// Round 5
// 1206.643 us; speedup vs baseline: 1.2590x; 1.2590x over previous
//
#include <hip/hip_runtime.h>
#include <hip/hip_bf16.h>
#include <math.h>
#include <stdint.h>

// ---------------------------------------------------------------------------
// GCN 4-layer, bf16 datapath:
//   h = relu( A_w @ (h @ W) + b ) x4, then log_softmax (fp32 out).
//   - dst-CSR built once per call; edges packed u32 (src<<15 | w*32767)
//   - CSR scatter is 2-phase bucket-binned (dst>>8) so the final scatter
//     writes land in ~32KB windows (line-coalesced) instead of random 4B/64B
//   - GEMM: bf16 MFMA 16x16x32, tile 128x64, BK=64, global_load_lds staging
//   - SpMM: one wave/dst node (row-major support), U=8 gathers in flight,
//     nontemporal output stores, fused bias+relu
// ---------------------------------------------------------------------------

#define WAVE 64
#define NBK 512          // scatter buckets (dst >> 8)
#define CHA 8192         // edges per phaseA block
typedef __attribute__((ext_vector_type(8))) short short8;
typedef __attribute__((ext_vector_type(4))) float floatx4;

__device__ __forceinline__ void async_copy16(const void* g, void* l) {
    __builtin_amdgcn_global_load_lds(
        (const __attribute__((address_space(1))) void*)g,
        (__attribute__((address_space(3))) void*)l, 16, 0, 0);
}
__device__ __forceinline__ float bf2f(unsigned short u) {
    union { unsigned int i; float f; } x; x.i = ((unsigned int)u) << 16; return x.f;
}

// ---------------- setup conversions ----------------

__global__ __launch_bounds__(256) void convert_x_kernel(const float* __restrict__ in,
                                                        __hip_bfloat16* __restrict__ out,
                                                        long n4) {
    long i = ((long)blockIdx.x * 256 + threadIdx.x);
    if (i >= n4) return;
    const float4 v = *(const float4*)(in + i * 4);
    __hip_bfloat16* o = out + i * 4;
    o[0] = __float2bfloat16(v.x); o[1] = __float2bfloat16(v.y);
    o[2] = __float2bfloat16(v.z); o[3] = __float2bfloat16(v.w);
}

// All weight transposes + bias pad in ONE kernel (launch-gap trim).
// Segments: Wt1 131072 | Wt2 32768 | Wt3 8192 | Wt4 4096 | b4p 64
__global__ __launch_bounds__(256) void prep_weights_kernel(
        const float* __restrict__ W1, const float* __restrict__ W2,
        const float* __restrict__ W3, const float* __restrict__ W4,
        const float* __restrict__ b4,
        __hip_bfloat16* __restrict__ Wt1, __hip_bfloat16* __restrict__ Wt2,
        __hip_bfloat16* __restrict__ Wt3, __hip_bfloat16* __restrict__ Wt4,
        float* __restrict__ b4p) {
    int idx = blockIdx.x * 256 + threadIdx.x;
    if (idx < 131072) {                       // Wt1: K=512 N=256
        int n = idx >> 9, k = idx & 511;
        Wt1[idx] = __float2bfloat16(W1[(size_t)k * 256 + n]);
    } else if (idx < 131072 + 32768) {        // Wt2: K=256 N=128
        int l = idx - 131072;
        int n = l >> 8, k = l & 255;
        Wt2[l] = __float2bfloat16(W2[(size_t)k * 128 + n]);
    } else if (idx < 131072 + 32768 + 8192) { // Wt3: K=128 N=64
        int l = idx - 131072 - 32768;
        int n = l >> 7, k = l & 127;
        Wt3[l] = __float2bfloat16(W3[(size_t)k * 64 + n]);
    } else if (idx < 131072 + 32768 + 8192 + 4096) { // Wt4: K=64 N=40 pad 64
        int l = idx - 131072 - 32768 - 8192;
        int n = l >> 6, k = l & 63;
        float v = (n < 40) ? W4[(size_t)k * 40 + n] : 0.f;
        Wt4[l] = __float2bfloat16(v);
    } else if (idx < 131072 + 32768 + 8192 + 4096 + 64) {
        int l = idx - 131072 - 32768 - 8192 - 4096;
        b4p[l] = (l < 40) ? b4[l] : 0.f;
    }
}

// ---------------- CSR build ----------------

__global__ __launch_bounds__(256) void hist_kernel(const int* __restrict__ dst,
                                                   int nE, int* __restrict__ counts) {
    int i = blockIdx.x * 256 + threadIdx.x;
    if (i < nE) atomicAdd(&counts[dst[i]], 1);
}

__global__ __launch_bounds__(1024) void scan1_kernel(const int* __restrict__ counts,
                                                     int n, int* __restrict__ partial,
                                                     int* __restrict__ bsum) {
    __shared__ int sm[1024];
    int tid = threadIdx.x;
    int i = blockIdx.x * 1024 + tid;
    int x = (i < n) ? counts[i] : 0;
    sm[tid] = x;
    __syncthreads();
    for (int off = 1; off < 1024; off <<= 1) {
        int add = 0;
        if (tid >= off) add = sm[tid - off];
        __syncthreads();
        if (tid >= off) sm[tid] += add;
        __syncthreads();
    }
    int incl = sm[tid];
    if (i < n) partial[i] = incl - x;
    if (tid == 1023) bsum[blockIdx.x] = incl;
}

__global__ __launch_bounds__(1024) void scan2_kernel(const int* __restrict__ bsum,
                                                     int nb, int* __restrict__ boff) {
    __shared__ int sm[1024];
    int tid = threadIdx.x;
    int x = (tid < nb) ? bsum[tid] : 0;
    sm[tid] = x;
    __syncthreads();
    for (int off = 1; off < 1024; off <<= 1) {
        int add = 0;
        if (tid >= off) add = sm[tid - off];
        __syncthreads();
        if (tid >= off) sm[tid] += add;
        __syncthreads();
    }
    if (tid < nb) boff[tid] = sm[tid] - x;
}

// finalize row_ptr; init row_cur and per-bucket cursors gcur[b]=row_ptr[b<<8]
__global__ __launch_bounds__(256) void scan3_kernel(int* __restrict__ row_ptr,
                                                    const int* __restrict__ boff,
                                                    int n, int nE,
                                                    int* __restrict__ row_cur,
                                                    int* __restrict__ gcur) {
    int i = blockIdx.x * 256 + threadIdx.x;
    if (i < n) {
        int v = row_ptr[i] + boff[i >> 10];
        row_ptr[i] = v;
        row_cur[i] = v;
        if ((i & 255) == 0) gcur[i >> 8] = v;
    }
    if (i == 0) row_ptr[n] = nE;
}

// Phase A: bucket edges by dst>>8 into E2 staging (u64: .y=dst, .x=src<<15|w15).
// Per-block LDS histogram + one global reservation per (block,bucket); writes
// land as ~16-entry runs per bucket region (line-friendly).
__global__ __launch_bounds__(256) void scatter_phaseA(const int* __restrict__ src,
                                                      const int* __restrict__ dst,
                                                      const float* __restrict__ ew,
                                                      int nE,
                                                      int* __restrict__ gcur,
                                                      uint2* __restrict__ E2) {
    __shared__ int hist[NBK];
    __shared__ int cur[NBK];
    const int t = threadIdx.x;
    const long e0 = (long)blockIdx.x * CHA;
    const int cnt = (int)((nE - e0 < CHA) ? (nE - e0) : CHA);

    for (int i = t; i < NBK; i += 256) hist[i] = 0;
    __syncthreads();
    for (int i = t; i < cnt; i += 256)
        atomicAdd(&hist[dst[e0 + i] >> 8], 1);
    __syncthreads();
    for (int i = t; i < NBK; i += 256) {
        int h = hist[i];
        cur[i] = h ? atomicAdd(&gcur[i], h) : 0;   // global base for this block
    }
    __syncthreads();
    for (int i = t; i < cnt; i += 256) {
        int d = dst[e0 + i];
        unsigned int w15 = (unsigned int)(ew[e0 + i] * 32767.f + 0.5f);
        if (w15 > 32767u) w15 = 32767u;
        int pos = atomicAdd(&cur[d >> 8], 1);      // LDS atomic -> global slot
        E2[pos] = make_uint2(((unsigned int)src[e0 + i] << 15) | w15,
                             (unsigned int)d);
    }
}

// Phase B: exact CSR placement. Each bucket's writes span only ~32KB of
// edge_pk, so the 4B scatters coalesce in L2 instead of costing a line each.
__global__ __launch_bounds__(256) void scatter_phaseB(const uint2* __restrict__ E2,
                                                      int nE,
                                                      int* __restrict__ row_cur,
                                                      unsigned int* __restrict__ edge_pk) {
    int i = blockIdx.x * 256 + threadIdx.x;
    if (i < nE) {
        uint2 e = E2[i];
        int pos = atomicAdd(&row_cur[e.y], 1);
        edge_pk[pos] = e.x;
    }
}

// ---------------- bf16 MFMA GEMM: C[M,Npitch] = A[M,K] @ Wt[Npitch,K]^T -----

__global__ __launch_bounds__(256) void gemm_bf16(const __hip_bfloat16* __restrict__ A,
                                                 const __hip_bfloat16* __restrict__ Wt,
                                                 __hip_bfloat16* __restrict__ C,
                                                 int M, int K, int Npitch) {
    __shared__ __align__(16) __hip_bfloat16 sA[128 * 64];  // [row][k], 128B rows
    __shared__ __align__(16) __hip_bfloat16 sB[64 * 64];   // [n][k],   128B rows
    const int t = threadIdx.x;
    const int lane = t & 63;
    const int w = t >> 6;
    const int wy = w >> 1, wx = w & 1;
    const int quad = lane >> 4;
    const int l16 = lane & 15;
    const int row0 = blockIdx.y * 128;
    const int col0 = blockIdx.x * 64;

    floatx4 acc[4][2];
#pragma unroll
    for (int mt = 0; mt < 4; mt++)
#pragma unroll
        for (int nt = 0; nt < 2; nt++) acc[mt][nt] = 0;

    const int arow = t >> 3;
    const int koff = (t & 7) * 8;

    for (int k0 = 0; k0 < K; k0 += 64) {
#pragma unroll
        for (int r = 0; r < 4; r++) {
            int gm = row0 + r * 32 + arow;
            int gmc = (gm < M) ? gm : 0;
            async_copy16(A + (size_t)gmc * K + k0 + koff,
                         (char*)sA + r * 4096 + t * 16);
        }
#pragma unroll
        for (int r = 0; r < 2; r++) {
            int n = r * 32 + arow;
            async_copy16(Wt + (size_t)(col0 + n) * K + k0 + koff,
                         (char*)sB + r * 4096 + t * 16);
        }
        __syncthreads();

        short8 af[4][2], bfr[2][2];
#pragma unroll
        for (int mt = 0; mt < 4; mt++)
#pragma unroll
            for (int kk = 0; kk < 2; kk++)
                af[mt][kk] = *(const short8*)((const char*)sA +
                             (wy * 64 + mt * 16 + l16) * 128 + kk * 64 + quad * 16);
#pragma unroll
        for (int nt = 0; nt < 2; nt++)
#pragma unroll
            for (int kk = 0; kk < 2; kk++)
                bfr[nt][kk] = *(const short8*)((const char*)sB +
                              (wx * 32 + nt * 16 + l16) * 128 + kk * 64 + quad * 16);
#pragma unroll
        for (int kk = 0; kk < 2; kk++)
#pragma unroll
            for (int mt = 0; mt < 4; mt++)
#pragma unroll
                for (int nt = 0; nt < 2; nt++)
                    acc[mt][nt] = __builtin_amdgcn_mfma_f32_16x16x32_bf16(
                        af[mt][kk], bfr[nt][kk], acc[mt][nt], 0, 0, 0);
        __syncthreads();
    }

#pragma unroll
    for (int mt = 0; mt < 4; mt++) {
#pragma unroll
        for (int nt = 0; nt < 2; nt++) {
            int gn = col0 + wx * 32 + nt * 16 + l16;
            int gmb = row0 + wy * 64 + mt * 16 + quad * 4;
#pragma unroll
            for (int r = 0; r < 4; r++) {
                int gm = gmb + r;
                if (gm < M)
                    C[(size_t)gm * Npitch + gn] = __float2bfloat16(acc[mt][nt][r]);
            }
        }
    }
}

// ---------------- SpMM (CSR by dst) + bias + relu, bf16 gathers -------------
// One wave per dst node; U gathers in flight; nontemporal output stores.

__device__ __forceinline__ void store_nt(__hip_bfloat16* p, float v) {
    __hip_bfloat16 b = __float2bfloat16(v);
    __builtin_nontemporal_store(*(unsigned short*)&b, (unsigned short*)p);
}
__device__ __forceinline__ void store_nt(float* p, float v) {
    __builtin_nontemporal_store(v, p);
}

template <int D, int VEC, int U, typename OT>
__global__ __launch_bounds__(256) void spmm_bias_relu(const int* __restrict__ row_ptr,
                                                      const unsigned int* __restrict__ edge_pk,
                                                      const __hip_bfloat16* __restrict__ support,
                                                      const float* __restrict__ bias,
                                                      OT* __restrict__ out,
                                                      int n_nodes) {
    int node = blockIdx.x * (256 / WAVE) + (threadIdx.x >> 6);
    int lane = threadIdx.x & 63;
    if (node >= n_nodes) return;
    node = __builtin_amdgcn_readfirstlane(node);
    int e = row_ptr[node];
    const int end = row_ptr[node + 1];
    const int col = lane * VEC;
    const unsigned short* sup = (const unsigned short*)support + col;

    float acc[VEC];
#pragma unroll
    for (int i = 0; i < VEC; i++) acc[i] = 0.f;

    while (e < end) {
        unsigned int pk[U];
#pragma unroll
        for (int u = 0; u < U; u++) {
            int idx = e + u;
            if (idx >= end) idx = end - 1;       // clamp stays in this row
            pk[u] = edge_pk[idx];
        }
        unsigned int srcs[U]; float wts[U];
#pragma unroll
        for (int u = 0; u < U; u++) {
            srcs[u] = pk[u] >> 15;
            float wq = (float)(pk[u] & 0x7fffu) * (1.f / 32767.f);
            wts[u] = (e + u < end) ? wq : 0.f;   // tail contributes 0
        }
        if (VEC == 4) {
            ushort4 v[U];
#pragma unroll
            for (int u = 0; u < U; u++)
                v[u] = *(const ushort4*)(sup + (size_t)srcs[u] * D);
#pragma unroll
            for (int u = 0; u < U; u++) {
                acc[0] += bf2f(v[u].x) * wts[u]; acc[1] += bf2f(v[u].y) * wts[u];
                acc[2] += bf2f(v[u].z) * wts[u]; acc[3] += bf2f(v[u].w) * wts[u];
            }
        } else if (VEC == 2) {
            ushort2 v[U];
#pragma unroll
            for (int u = 0; u < U; u++)
                v[u] = *(const ushort2*)(sup + (size_t)srcs[u] * D);
#pragma unroll
            for (int u = 0; u < U; u++) {
                acc[0] += bf2f(v[u].x) * wts[u]; acc[1] += bf2f(v[u].y) * wts[u];
            }
        } else {
            unsigned short v[U];
#pragma unroll
            for (int u = 0; u < U; u++) v[u] = sup[(size_t)srcs[u] * D];
#pragma unroll
            for (int u = 0; u < U; u++) acc[0] += bf2f(v[u]) * wts[u];
        }
        e += U;
    }
#pragma unroll
    for (int i = 0; i < VEC; i++) {
        float r = acc[i] + bias[col + i];
        store_nt(&out[(size_t)node * D + col + i], r > 0.f ? r : 0.f);
    }
}

// ---------------- log_softmax over 40 classes (input pitch 64, fp32) --------

__global__ __launch_bounds__(256) void logsoftmax40_kernel(const float* __restrict__ h,
                                                           float* __restrict__ out,
                                                           int n_nodes) {
    int row = blockIdx.x * (256 / WAVE) + (threadIdx.x >> 6);
    int lane = threadIdx.x & 63;
    if (row >= n_nodes) return;
    float v = (lane < 40) ? h[(size_t)row * 64 + lane] : -INFINITY;
    float m = v;
#pragma unroll
    for (int off = 32; off; off >>= 1) m = fmaxf(m, __shfl_xor(m, off));
    float e = (lane < 40) ? __expf(v - m) : 0.f;
    float s = e;
#pragma unroll
    for (int off = 32; off; off >>= 1) s += __shfl_xor(s, off);
    if (lane < 40) out[(size_t)row * 40 + lane] = v - m - __logf(s);
}

// ---------------- launch ----------------------------------------------------

extern "C" void kernel_launch(void* const* d_in, const int* in_sizes, int n_in,
                              void* d_out, int out_size, void* d_ws, size_t ws_size,
                              hipStream_t stream) {
    const float* x    = (const float*)d_in[0];
    const int*   esrc = (const int*)d_in[1];
    const int*   edst = (const int*)d_in[2];
    const float* ew   = (const float*)d_in[3];
    const float* Wm[4] = {(const float*)d_in[4], (const float*)d_in[6],
                          (const float*)d_in[8], (const float*)d_in[10]};
    const float* bm[4] = {(const float*)d_in[5], (const float*)d_in[7],
                          (const float*)d_in[9], (const float*)d_in[11]};
    const int NFEAT = 512;
    const int n_nodes = in_sizes[0] / NFEAT;
    const int n_edges = in_sizes[1];
    float* out = (float*)d_out;

    // --- workspace carve ---
    char* wsp = (char*)d_ws;
    size_t off = 0;
    auto alloc = [&](size_t bytes) -> void* {
        void* p = wsp + off;
        off += (bytes + 255) & ~(size_t)255;
        return p;
    };
    __hip_bfloat16* Xb = (__hip_bfloat16*)alloc((size_t)n_nodes * 512 * sizeof(__hip_bfloat16));
    __hip_bfloat16* Sb = (__hip_bfloat16*)alloc((size_t)n_nodes * 256 * sizeof(__hip_bfloat16));
    __hip_bfloat16* Hb = (__hip_bfloat16*)alloc((size_t)n_nodes * 256 * sizeof(__hip_bfloat16));
    __hip_bfloat16* Wt1 = (__hip_bfloat16*)alloc(256 * 512 * sizeof(__hip_bfloat16));
    __hip_bfloat16* Wt2 = (__hip_bfloat16*)alloc(128 * 256 * sizeof(__hip_bfloat16));
    __hip_bfloat16* Wt3 = (__hip_bfloat16*)alloc(64 * 128 * sizeof(__hip_bfloat16));
    __hip_bfloat16* Wt4 = (__hip_bfloat16*)alloc(64 * 64 * sizeof(__hip_bfloat16));
    float* b4p     = (float*)alloc(64 * sizeof(float));
    int*   counts  = (int*)alloc((size_t)n_nodes * sizeof(int));
    int*   row_ptr = (int*)alloc(((size_t)n_nodes + 1) * sizeof(int));
    int*   row_cur = (int*)alloc((size_t)n_nodes * sizeof(int));
    int*   bsum    = (int*)alloc(1024 * sizeof(int));
    int*   boff    = (int*)alloc(1024 * sizeof(int));
    int*   gcur    = (int*)alloc(NBK * sizeof(int));
    unsigned int* edge_pk = (unsigned int*)alloc((size_t)n_edges * sizeof(unsigned int));
    // E2 staging (8B/edge) aliases Hb: Hb is first written by L1 SpMM, which
    // runs after phaseB completes (same stream) -> safe.
    uint2* E2 = (uint2*)Hb;
    // G4 (L4 fp32 output, pitch 64) aliases Xb — Xb is dead after the L1 GEMM.
    float* G4 = (float*)Xb;
    (void)ws_size;

    // --- conversions ---
    long n4 = (long)n_nodes * 512 / 4;
    convert_x_kernel<<<(int)((n4 + 255) / 256), 256, 0, stream>>>(x, Xb, n4);
    prep_weights_kernel<<<(131072 + 32768 + 8192 + 4096 + 64 + 255) / 256, 256, 0, stream>>>(
        Wm[0], Wm[1], Wm[2], Wm[3], bm[3], Wt1, Wt2, Wt3, Wt4, b4p);

    // --- CSR build ---
    hipMemsetAsync(counts, 0, (size_t)n_nodes * sizeof(int), stream);
    hist_kernel<<<(n_edges + 255) / 256, 256, 0, stream>>>(edst, n_edges, counts);
    int nb = (n_nodes + 1023) / 1024;
    scan1_kernel<<<nb, 1024, 0, stream>>>(counts, n_nodes, row_ptr, bsum);
    scan2_kernel<<<1, 1024, 0, stream>>>(bsum, nb, boff);
    scan3_kernel<<<(n_nodes + 255) / 256, 256, 0, stream>>>(row_ptr, boff, n_nodes,
                                                            n_edges, row_cur, gcur);
    scatter_phaseA<<<(n_edges + CHA - 1) / CHA, 256, 0, stream>>>(esrc, edst, ew,
                                                                  n_edges, gcur, E2);
    scatter_phaseB<<<(n_edges + 255) / 256, 256, 0, stream>>>(E2, n_edges,
                                                              row_cur, edge_pk);

    // --- layers ---
    auto gemm = [&](const __hip_bfloat16* A, const __hip_bfloat16* Wt,
                    __hip_bfloat16* C, int K, int Npitch) {
        dim3 grid(Npitch / 64, (n_nodes + 127) / 128);
        gemm_bf16<<<grid, 256, 0, stream>>>(A, Wt, C, n_nodes, K, Npitch);
    };
    int spmm_blocks = (n_nodes + 3) / 4;

    // L1: 512 -> 256
    gemm(Xb, Wt1, Sb, 512, 256);
    spmm_bias_relu<256, 4, 8, __hip_bfloat16><<<spmm_blocks, 256, 0, stream>>>(
        row_ptr, edge_pk, Sb, bm[0], Hb, n_nodes);
    // L2: 256 -> 128
    gemm(Hb, Wt2, Sb, 256, 128);
    spmm_bias_relu<128, 2, 8, __hip_bfloat16><<<spmm_blocks, 256, 0, stream>>>(
        row_ptr, edge_pk, Sb, bm[1], Hb, n_nodes);
    // L3: 128 -> 64
    gemm(Hb, Wt3, Sb, 128, 64);
    spmm_bias_relu<64, 1, 8, __hip_bfloat16><<<spmm_blocks, 256, 0, stream>>>(
        row_ptr, edge_pk, Sb, bm[2], Hb, n_nodes);
    // L4: 64 -> 40 (N padded to 64; padded support cols/bias are zero)
    gemm(Hb, Wt4, Sb, 64, 64);
    spmm_bias_relu<64, 1, 8, float><<<spmm_blocks, 256, 0, stream>>>(
        row_ptr, edge_pk, Sb, b4p, G4, n_nodes);

    // final log_softmax (reads pitch-64 fp32, writes [n,40] fp32)
    logsoftmax40_kernel<<<(n_nodes + 3) / 4, 256, 0, stream>>>(G4, out, n_nodes);
}